// Round 6
// baseline (409.978 us; speedup 1.0000x reference)
//
#include <hip/hip_runtime.h>
#include <cmath>
#include <climits>

#define EMBED 64
#define KTOP 11          // top_n + 1 (self match included, dropped at output)
#define NB   512         // 2 blocks/CU x 256 CU, all resident
#define BLOCK1 256       // 4 waves; 2 buf x 4 waves x 8KB = 64KB static LDS
#define NW1  (BLOCK1 / 64)
#define BLOCK2 256
#define NW2  (BLOCK2 / 64)
#define ATILE 8192       // DMA half of a super-tile: 32 rows
#define SUPER 16384      // 64 rows: 32 via DMA->LDS + 32 via VGPR loads

typedef const __attribute__((address_space(1))) void gv_t;
typedef __attribute__((address_space(3))) void lv_t;

// Insert (v,i) into per-thread sorted top-KTOP list (desc value, asc index).
__device__ __forceinline__ void topk_insert(float (&vals)[KTOP], int (&idxs)[KTOP],
                                            float v, int i) {
  float last = vals[KTOP - 1];
  if (v < last) return;
  if (v == last && i >= idxs[KTOP - 1]) return;
  float cv = v; int ci = i;
#pragma unroll
  for (int j = 0; j < KTOP; ++j) {
    bool better = (cv > vals[j]) || (cv == vals[j] && ci < idxs[j]);
    if (better) {
      float tv = vals[j]; int ti = idxs[j];
      vals[j] = cv; idxs[j] = ci;
      cv = tv; ci = ti;
    }
  }
}

// Merge 64 lanes' sorted top-KTOP lists into wave top-KTOP, written to LDS.
__device__ __forceinline__ void wave_merge(float (&vals)[KTOP], int (&idxs)[KTOP],
                                           float* wv, int* wi, int lane) {
#pragma unroll
  for (int round = 0; round < KTOP; ++round) {
    float v = vals[0]; int i = idxs[0]; int l = lane;
#pragma unroll
    for (int off = 32; off > 0; off >>= 1) {
      float ov = __shfl_xor(v, off, 64);
      int   oi = __shfl_xor(i, off, 64);
      int   ol = __shfl_xor(l, off, 64);
      if (ov > v || (ov == v && oi < i)) { v = ov; i = oi; l = ol; }
    }
    if (l == lane) {  // winner pops its head
#pragma unroll
      for (int j = 0; j < KTOP - 1; ++j) { vals[j] = vals[j + 1]; idxs[j] = idxs[j + 1]; }
      vals[KTOP - 1] = -INFINITY; idxs[KTOP - 1] = INT_MAX;
    }
    if (lane == 0) { wv[round] = v; wi[round] = i; }
  }
}

// 8 x 1KB global->LDS DMA for the 32-row A-half of a super-tile.
__device__ __forceinline__ void dmaA(const char* g, size_t byteBase,
                                     int lane, char* lds, size_t maxOff) {
  if (byteBase + ATILE - 16 <= maxOff) {
#pragma unroll
    for (int j = 0; j < 8; ++j)
      __builtin_amdgcn_global_load_lds(
          (gv_t*)(g + byteBase + (size_t)j * 1024 + (size_t)lane * 16),
          (lv_t*)(lds + j * 1024), 16, 0, 0);
  } else {
#pragma unroll
    for (int j = 0; j < 8; ++j) {
      size_t off = byteBase + (size_t)j * 1024 + (size_t)lane * 16;
      if (off > maxOff) off = maxOff;
      __builtin_amdgcn_global_load_lds(
          (gv_t*)(g + off), (lv_t*)(lds + j * 1024), 16, 0, 0);
    }
  }
}

__global__ __launch_bounds__(BLOCK1, 2) void sim_pass1(
    const float* __restrict__ emb, const int* __restrict__ user_id,
    float* __restrict__ cand_val, int* __restrict__ cand_idx, int V) {
  __shared__ __align__(16) char smem[2 * NW1 * ATILE];  // 64 KB

  const int lane = threadIdx.x & 63;
  const int wid  = threadIdx.x >> 6;
  const int uid  = *user_id;

  const float4* trow = (const float4*)(emb + (size_t)uid * EMBED);
  // A-half target chunks (rotated, per round 4's verified layout):
  float4 tvA[8];
#pragma unroll
  for (int j = 0; j < 8; ++j) tvA[j] = trow[(lane >> 5) * 8 + ((j + lane) & 7)];
  // B-half target chunk (per round 5's verified layout):
  const float4 tgtB = trow[lane & 15];

  float vals[KTOP]; int idxs[KTOP];
#pragma unroll
  for (int j = 0; j < KTOP; ++j) { vals[j] = -INFINITY; idxs[j] = INT_MAX; }

  const int gw = blockIdx.x * NW1 + wid;
  const int nW = NB * NW1;
  const int nSuper = (V + 63) >> 6;
  const char* g = (const char*)emb;
  const float4* base = (const float4*)emb;
  const size_t maxOff = (size_t)V * 256 - 16;
  const size_t maxQ   = (size_t)V * 16 - 1;
  char* myLds = smem + wid * (2 * ATILE);

  int p = 0;
  int s = gw;
  if (s < nSuper) dmaA(g, (size_t)s * SUPER, lane, myLds, maxOff);

  int par = 0;
  for (; s < nSuper; s += nW, par ^= 1) {
    // ---- B-half VGPR loads (rows s*64+32 .. +63): 8 contiguous 1KB ----
    const size_t q0 = (size_t)s * 1024 + 512 + lane;
    float4 v[8];
#pragma unroll
    for (int j = 0; j < 8; ++j) {
      size_t q = q0 + (size_t)j * 64;
      if (q > maxQ) q = maxQ;   // ragged-tail only; guarded at insert
      v[j] = base[q];
    }
    asm volatile("" ::: "memory");  // pin issue order: B_k before A_{k+1} DMA

    const int next = s + nW;
    const bool pf = next < nSuper;
    if (pf) {
      dmaA(g, (size_t)next * SUPER, lane, myLds + (p ^ 1) * ATILE, maxOff);
      asm volatile("s_waitcnt vmcnt(16)" ::: "memory");  // A_k DMA retired
    } else {
      asm volatile("s_waitcnt vmcnt(8)" ::: "memory");   // A_k DMA retired
    }

    // ---- A-half compute from LDS (round-4 verified): half-row per lane ----
    {
      const char* lb = myLds + p * ATILE + (lane & 31) * 256 + (lane >> 5) * 128;
      float dot = 0.f, nr = 0.f;
#pragma unroll
      for (int j = 0; j < 8; ++j) {
        float4 x = *(const float4*)(lb + ((j + lane) & 7) * 16);
        float4 t = tvA[j];
        dot = fmaf(x.x, t.x, dot); dot = fmaf(x.y, t.y, dot);
        dot = fmaf(x.z, t.z, dot); dot = fmaf(x.w, t.w, dot);
        nr  = fmaf(x.x, x.x, nr);  nr  = fmaf(x.y, x.y, nr);
        nr  = fmaf(x.z, x.z, nr);  nr  = fmaf(x.w, x.w, nr);
      }
      dot += __shfl_xor(dot, 32, 64);
      nr  += __shfl_xor(nr,  32, 64);
      const int r = (s << 6) + (lane & 31);
      if ((lane >> 5) == par && r < V)
        topk_insert(vals, idxs, dot / sqrtf(nr), r);  // /||target|| deferred
    }

    if (pf) asm volatile("s_waitcnt vmcnt(8)" ::: "memory");  // B_k retired
    else    asm volatile("s_waitcnt vmcnt(0)" ::: "memory");

    // ---- B-half compute (round-5 verified 8-seg reduce-scatter) ----
    {
      float d[8], n[8];
#pragma unroll
      for (int j = 0; j < 8; ++j) {
        float4 x = v[j];
        float dd =        x.x * tgtB.x;
        dd = fmaf(x.y, tgtB.y, dd); dd = fmaf(x.z, tgtB.z, dd); dd = fmaf(x.w, tgtB.w, dd);
        float nn =        x.x * x.x;
        nn = fmaf(x.y, x.y, nn);    nn = fmaf(x.z, x.z, nn);    nn = fmaf(x.w, x.w, nn);
        d[j] = dd; n[j] = nn;
      }
#pragma unroll
      for (int st = 0; st < 3; ++st) {
        const int m = 1 << st;
        const int b = (lane >> st) & 1;
#pragma unroll
        for (int k = 0; k < (8 >> (st + 1)); ++k) {
          float dk = b ? d[2 * k + 1] : d[2 * k];
          float ds = b ? d[2 * k]     : d[2 * k + 1];
          float nk = b ? n[2 * k + 1] : n[2 * k];
          float ns = b ? n[2 * k]     : n[2 * k + 1];
          d[k] = dk + __shfl_xor(ds, m, 64);
          n[k] = nk + __shfl_xor(ns, m, 64);
        }
      }
      // combine the two 8-chunk halves (lanes l and l^8 hold same row)
      d[0] += __shfl_xor(d[0], 8, 64);
      n[0] += __shfl_xor(n[0], 8, 64);
      const int r = (s << 6) + 32 + ((lane & 7) << 2) + (lane >> 4);
      if (((lane >> 3) & 1) == par && r < V)
        topk_insert(vals, idxs, d[0] / sqrtf(n[0]), r);
    }
    p ^= 1;
  }

  // Buffers dead; alias merge scratch into smem.
  __syncthreads();
  float* wv = (float*)smem;
  int*   wi = (int*)(smem + NW1 * KTOP * sizeof(float));
  wave_merge(vals, idxs, &wv[wid * KTOP], &wi[wid * KTOP], lane);
  __syncthreads();

  if (wid == 0) {  // wave 0 merges NW1*KTOP entries -> block top-KTOP
    float v = (lane < NW1 * KTOP) ? wv[lane] : -INFINITY;
    int   i = (lane < NW1 * KTOP) ? wi[lane] : INT_MAX;
#pragma unroll
    for (int round = 0; round < KTOP; ++round) {
      float bv = v; int bi = i; int bl = lane;
#pragma unroll
      for (int off = 32; off > 0; off >>= 1) {
        float ov = __shfl_xor(bv, off, 64);
        int   oi = __shfl_xor(bi, off, 64);
        int   ol = __shfl_xor(bl, off, 64);
        if (ov > bv || (ov == bv && oi < bi)) { bv = ov; bi = oi; bl = ol; }
      }
      if (bl == lane) { v = -INFINITY; i = INT_MAX; }
      if (lane == 0) {
        cand_val[blockIdx.x * KTOP + round] = bv;
        cand_idx[blockIdx.x * KTOP + round] = bi;
      }
    }
  }
}

__global__ __launch_bounds__(BLOCK2) void sim_pass2(
    const float* __restrict__ emb, const int* __restrict__ user_id,
    const float* __restrict__ cand_val, const int* __restrict__ cand_idx,
    float* __restrict__ out, int topn, int ncand) {
  __shared__ float wv[NW2 * KTOP];
  __shared__ int   wi[NW2 * KTOP];
  __shared__ float s_nt;

  const int lane = threadIdx.x & 63;
  const int wid  = threadIdx.x >> 6;

  if (wid == 0) {  // ||target|| on wave 0
    const int uid = *user_id;
    float x = (lane < EMBED) ? emb[(size_t)uid * EMBED + lane] : 0.f;
    float s = x * x;
#pragma unroll
    for (int off = 32; off > 0; off >>= 1) s += __shfl_xor(s, off, 64);
    if (lane == 0) s_nt = sqrtf(s);
  }

  float vals[KTOP]; int idxs[KTOP];
#pragma unroll
  for (int j = 0; j < KTOP; ++j) { vals[j] = -INFINITY; idxs[j] = INT_MAX; }

  for (int c = threadIdx.x; c < ncand; c += BLOCK2)
    topk_insert(vals, idxs, cand_val[c], cand_idx[c]);

  wave_merge(vals, idxs, &wv[wid * KTOP], &wi[wid * KTOP], lane);
  __syncthreads();

  if (wid == 0) {
    float v = (lane < NW2 * KTOP) ? wv[lane] : -INFINITY;
    int   i = (lane < NW2 * KTOP) ? wi[lane] : INT_MAX;
    const float nt = s_nt;
#pragma unroll
    for (int round = 0; round < KTOP; ++round) {
      float bv = v; int bi = i; int bl = lane;
#pragma unroll
      for (int off = 32; off > 0; off >>= 1) {
        float ov = __shfl_xor(bv, off, 64);
        int   oi = __shfl_xor(bi, off, 64);
        int   ol = __shfl_xor(bl, off, 64);
        if (ov > bv || (ov == bv && oi < bi)) { bv = ov; bi = oi; bl = ol; }
      }
      if (bl == lane) { v = -INFINITY; i = INT_MAX; }
      // round 0 is the self match -> dropped (matches ref's top_vals[1:])
      if (lane == 0 && round >= 1 && round <= topn) {
        out[round - 1]        = bv / nt;       // similarity value
        out[topn + round - 1] = (float)bi;     // index, as float
      }
    }
  }
}

extern "C" void kernel_launch(void* const* d_in, const int* in_sizes, int n_in,
                              void* d_out, int out_size, void* d_ws, size_t ws_size,
                              hipStream_t stream) {
  const float* emb = (const float*)d_in[0];
  const int*   uid = (const int*)d_in[1];
  const int V    = in_sizes[0] / EMBED;
  const int topn = out_size / 2;  // 10 -> KTOP = 11 covers it

  float* cand_val = (float*)d_ws;
  int*   cand_idx = (int*)((char*)d_ws + (size_t)NB * KTOP * sizeof(float));

  sim_pass1<<<NB, BLOCK1, 0, stream>>>(emb, uid, cand_val, cand_idx, V);
  sim_pass2<<<1, BLOCK2, 0, stream>>>(emb, uid, cand_val, cand_idx,
                                      (float*)d_out, topn, NB * KTOP);
}